// Round 5
// baseline (204.610 us; speedup 1.0000x reference)
//
#include <hip/hip_runtime.h>
#include <math.h>

constexpr int BN = 8192;
constexpr int MN = 6;

// E = -T*log2(e)*d2 with T=2:  E = 2TL*g - TL*sq_i - TL*sq_j,  L=log2(e)
constexpr float TL    = 2.8853900817779268f;   // 2*log2(e)
constexpr float SCL_Z = 2.4022448795936154f;   // sqrt(2*T*L)

typedef __bf16 bf16_t;
typedef bf16_t bf16x8 __attribute__((ext_vector_type(8)));
typedef float f32x4 __attribute__((ext_vector_type(4)));

union PK { bf16_t h[8]; uint4 u; };

__device__ __forceinline__ bf16x8 frag_of(uint4 u) {
    return __builtin_bit_cast(bf16x8, u);
}

__device__ __host__ __forceinline__ int midx(int a, int b) {
    // index into upper-triangle (a<=b) of 8x8, row-major packed
    return 8 * a - (a * (a - 1)) / 2 + (b - a);
}

// ---------------------------------------------------------------------------
// K0: blocks 0..191  -> pack MFMA fragments (one thread per (mode, row)).
//     blocks 192..223 -> angle second moments (36 pair moments + 8 sums).
// ---------------------------------------------------------------------------
__global__ __launch_bounds__(256) void prep_ang(const float* __restrict__ x,
                                                const float* __restrict__ ang,
                                                uint4* __restrict__ Ap,
                                                uint4* __restrict__ Bp,
                                                float* __restrict__ angp) {
    const int blk = blockIdx.x;
    const int tid = threadIdx.x;
    if (blk < 192) {
        int idx = blk * 256 + tid;
        int n = idx >> 13;
        int j = idx & (BN - 1);
        const float* p = x + (size_t)j * 48 + n * 8;

        PK zh, zl, a3, b3;
        float sq = 0.f;
#pragma unroll
        for (int k = 0; k < 8; ++k) {
            float v = p[k];
            sq = fmaf(v, v, sq);
            float z = SCL_Z * v;
            bf16_t h = (bf16_t)z;
            zh.h[k] = h;
            zl.h[k] = (bf16_t)(z - (float)h);
        }
        float s = -TL * sq;
        bf16_t sh = (bf16_t)s;
        bf16_t sl = (bf16_t)(s - (float)sh);
        bf16_t one = (bf16_t)1.0f, zero = (bf16_t)0.0f;
        a3.h[0] = one; a3.h[1] = one; a3.h[2] = sh;  a3.h[3] = sl;
        b3.h[0] = sh;  b3.h[1] = sl;  b3.h[2] = one; b3.h[3] = one;
#pragma unroll
        for (int k = 4; k < 8; ++k) { a3.h[k] = zero; b3.h[k] = zero; }

        size_t base = ((size_t)(n * 512 + (j >> 4))) * 64 + (j & 15);
        Ap[base +  0] = zh.u;
        Ap[base + 16] = zl.u;
        Ap[base + 32] = zh.u;
        Ap[base + 48] = a3.u;
        Bp[base +  0] = zh.u;
        Bp[base + 16] = zh.u;
        Bp[base + 32] = zl.u;
        Bp[base + 48] = b3.u;
    } else {
        const int i = (blk - 192) * 256 + tid;  // 32 blocks cover 8192 rows
        float v[8];
#pragma unroll
        for (int k = 0; k < 4; ++k) __sincosf(ang[i * 4 + k], &v[k], &v[4 + k]);
        float acc[44];
        int c = 0;
#pragma unroll
        for (int a = 0; a < 8; ++a)
#pragma unroll
            for (int bq = a; bq < 8; ++bq) acc[c++] = v[a] * v[bq];
#pragma unroll
        for (int a = 0; a < 8; ++a) acc[36 + a] = v[a];

#pragma unroll
        for (int q = 0; q < 44; ++q) {
            float s = acc[q];
            s += __shfl_xor(s, 1);  s += __shfl_xor(s, 2);
            s += __shfl_xor(s, 4);  s += __shfl_xor(s, 8);
            s += __shfl_xor(s, 16); s += __shfl_xor(s, 32);
            acc[q] = s;
        }
        __shared__ float sm[4][44];
        const int w = tid >> 6, lane = tid & 63;
        if (lane == 0)
#pragma unroll
            for (int q = 0; q < 44; ++q) sm[w][q] = acc[q];
        __syncthreads();
        if (tid < 44)
            angp[(blk - 192) * 44 + tid] =
                sm[0][tid] + sm[1][tid] + sm[2][tid] + sm[3][tid];
    }
}

// ---------------------------------------------------------------------------
// K1: pairwise kernel.  Block = (mode, 64-row group, col-half h).
// Grid 1536 x 512thr -> 12288 waves -> 8 resident waves/SIMD (hide mfma->exp).
// Wave w of half h sweeps col tiles jt = 2w+h + 16k, k=0..31 (interleaved).
// Per 2 tiles: {2 loads, 8 mfma (all first), 32 exp2, 32 add} branch-free.
// Partial row sums (this half's cols) -> Sh[h]; diag wave subtracts self-term.
// ---------------------------------------------------------------------------
__global__ __launch_bounds__(512, 8) void pair_mfma(const uint4* __restrict__ Ap,
                                                    const uint4* __restrict__ Bp,
                                                    float* __restrict__ Sh) {
    const int tid  = threadIdx.x;
    const int lane = tid & 63;
    const int w    = __builtin_amdgcn_readfirstlane(tid >> 6);
    const int b    = blockIdx.x;
    const int n    = b >> 8;          // mode
    const int rb   = (b >> 1) & 127;  // 64-row group
    const int h    = b & 1;           // column half (tile-parity)
    const int rb4  = rb * 4;          // first 16-row tile index
    const int base = 2 * w + h;       // first col tile for this wave

    bf16x8 af[4];
#pragma unroll
    for (int t = 0; t < 4; ++t)
        af[t] = frag_of(Ap[((size_t)(n * 512 + rb4 + t)) * 64 + lane]);

    float racc[16];
#pragma unroll
    for (int q = 0; q < 16; ++q) racc[q] = 0.f;

    const uint4* bbase = Bp + ((size_t)n * 512) * 64 + lane;
    const f32x4 z4 = {0.f, 0.f, 0.f, 0.f};

    // 32 tiles per wave: jt = base + 16k; 2 tiles per iteration.
    uint4 b0 = bbase[(size_t)base * 64];
    uint4 b1 = bbase[(size_t)(base + 16) * 64];
    for (int m = 0; m < 16; ++m) {
        const int jtA = base + 32 * m;
        // prefetch next iteration (over-read past Bp lands in Ap: harmless)
        uint4 p0 = bbase[(size_t)(jtA + 32) * 64];
        uint4 p1 = bbase[(size_t)(jtA + 48) * 64];

        bf16x8 bfA = frag_of(b0);
        bf16x8 bfB = frag_of(b1);
        f32x4 d0[4], d1[4];
#pragma unroll
        for (int t = 0; t < 4; ++t)
            d0[t] = __builtin_amdgcn_mfma_f32_16x16x32_bf16(af[t], bfA, z4, 0, 0, 0);
#pragma unroll
        for (int t = 0; t < 4; ++t)
            d1[t] = __builtin_amdgcn_mfma_f32_16x16x32_bf16(af[t], bfB, z4, 0, 0, 0);
#pragma unroll
        for (int t = 0; t < 4; ++t)
#pragma unroll
            for (int r = 0; r < 4; ++r)
                racc[t * 4 + r] += __builtin_amdgcn_exp2f(d0[t][r]);
#pragma unroll
        for (int t = 0; t < 4; ++t)
#pragma unroll
            for (int r = 0; r < 4; ++r)
                racc[t * 4 + r] += __builtin_amdgcn_exp2f(d1[t][r]);

        b0 = p0; b1 = p1;
    }

    // diagonal fix-up: wave owning col tile rb4+t subtracts self-pair exp(0)
#pragma unroll
    for (int t = 0; t < 4; ++t) {
        const int rel = rb4 + t - base;
        if (rel >= 0 && (rel & 15) == 0) {   // wave-uniform
            const int dd = (lane & 15) - 4 * (lane >> 4);
            bf16x8 bf = frag_of(bbase[(size_t)(rb4 + t) * 64]);
            f32x4 d = __builtin_amdgcn_mfma_f32_16x16x32_bf16(af[t], bf, z4, 0, 0, 0);
#pragma unroll
            for (int r = 0; r < 4; ++r)
                if (dd == r) racc[t * 4 + r] -= __builtin_amdgcn_exp2f(d[r]);
        }
    }

    // reduce each racc over the 16 lanes of its column group (low 4 lane bits)
#pragma unroll
    for (int q = 0; q < 16; ++q) {
        float v = racc[q];
        v += __shfl_xor(v, 1);
        v += __shfl_xor(v, 2);
        v += __shfl_xor(v, 4);
        v += __shfl_xor(v, 8);
        racc[q] = v;
    }

    __shared__ float smem[8][64];
    if ((lane & 15) == 0) {
        int g = lane >> 4;
#pragma unroll
        for (int t = 0; t < 4; ++t)
#pragma unroll
            for (int r = 0; r < 4; ++r)
                smem[w][t * 16 + g * 4 + r] = racc[t * 4 + r];
    }
    __syncthreads();

    if (tid < 64) {
        float s = 0.f;
#pragma unroll
        for (int ww = 0; ww < 8; ++ww) s += smem[ww][tid];
        Sh[h * (MN * BN) + n * BN + rb * 64 + tid] = s;
    }
}

// ---------------------------------------------------------------------------
// K2: merge halves, take log, per-block partial sums.  96 blocks x 512.
// Block b covers rows [b*512, b*512+512) of the 6*8192 flat space; each block
// is within a single mode (8192/512 = 16 blocks per mode).
// ---------------------------------------------------------------------------
__global__ __launch_bounds__(512) void log_red(const float* __restrict__ Sh,
                                               float* __restrict__ lp) {
    const int tid = threadIdx.x;
    const int idx = blockIdx.x * 512 + tid;
    float v = Sh[idx] + Sh[idx + MN * BN];
    float lg = logf(v);
    lg += __shfl_xor(lg, 1);
    lg += __shfl_xor(lg, 2);
    lg += __shfl_xor(lg, 4);
    lg += __shfl_xor(lg, 8);
    lg += __shfl_xor(lg, 16);
    lg += __shfl_xor(lg, 32);
    __shared__ float sm[8];
    if ((tid & 63) == 0) sm[tid >> 6] = lg;
    __syncthreads();
    if (tid == 0) {
        float s = 0.f;
#pragma unroll
        for (int i = 0; i < 8; ++i) s += sm[i];
        lp[blockIdx.x] = s;
    }
}

// ---------------------------------------------------------------------------
// K3: final assembly — mu/cov/spread from moments, per-mode unif, outputs.
// ---------------------------------------------------------------------------
__global__ __launch_bounds__(64) void final_asm(const float* __restrict__ angp,
                                                const float* __restrict__ lp,
                                                float* __restrict__ out) {
    const int tid = threadIdx.x;
    __shared__ float mom[44];

    if (tid < 44) {
        float s = 0.f;
        for (int bk = 0; bk < 32; ++bk) s += angp[bk * 44 + tid];
        mom[tid] = s;
    }
    __syncthreads();

    if (tid == 0) {
        float sm[4], cm[4];
#pragma unroll
        for (int k = 0; k < 4; ++k) {
            float S = mom[36 + k], C = mom[40 + k];
            float hyp = sqrtf(S * S + C * C);
            sm[k] = S / hyp;       // sin(mu_k)
            cm[k] = C / hyp;       // cos(mu_k)
        }
        auto COV = [&](int k, int l) -> float {
            int ks = k < l ? k : l, kl = k < l ? l : k;
            float mss = mom[midx(ks, kl)];
            float msc_kl = mom[midx(k, l + 4)];
            float msc_lk = mom[midx(l, k + 4)];
            float mcc = mom[midx(ks + 4, kl + 4)];
            return (cm[k] * cm[l] * mss - cm[k] * sm[l] * msc_kl -
                    sm[k] * cm[l] * msc_lk + sm[k] * sm[l] * mcc) *
                   (1.0f / (float)BN);
        };
        float var[4] = {COV(0, 0), COV(1, 1), COV(2, 2), COV(3, 3)};
        float spread = 0.f;
        const int pk[6] = {0, 0, 0, 1, 1, 2};
        const int pl[6] = {1, 2, 3, 2, 3, 3};
#pragma unroll
        for (int p = 0; p < 6; ++p) {
            float cv = COV(pk[p], pl[p]);
            float den = sqrtf(var[pk[p]] * var[pl[p]] + 1e-8f);
            float cr = cv / den;
            spread += cr * cr;
        }
        spread *= (1.0f / 6.0f);

        const float wgt[6] = {0.0f, 0.19615242270663188f, 0.4641016151377544f,
                              0.7320508075688773f, 0.9282032302755088f, 1.0f};
        const float logBm1 = logf((float)(BN - 1));
        float total_unif = 0.f, unif[6];
#pragma unroll
        for (int m = 0; m < 6; ++m) {
            float s = 0.f;
            for (int i = 0; i < 16; ++i) s += lp[m * 16 + i];
            unif[m] = s * (1.0f / (float)BN) - logBm1;
            total_unif += wgt[m] * unif[m];
        }
        out[0] = total_unif;
        out[1] = spread;
        out[2] = total_unif + spread;
#pragma unroll
        for (int m = 0; m < 6; ++m) out[3 + m] = unif[m];
    }
}

extern "C" void kernel_launch(void* const* d_in, const int* in_sizes, int n_in,
                              void* d_out, int out_size, void* d_ws, size_t ws_size,
                              hipStream_t stream) {
    const float* angles  = (const float*)d_in[0];   // (8192, 4) f32
    const float* fourier = (const float*)d_in[1];   // (8192, 48) f32
    float* out = (float*)d_out;                     // 9 floats

    char* ws = (char*)d_ws;
    uint4* Bp   = (uint4*)(ws + 0);                 // 3,145,728 B
    uint4* Ap   = (uint4*)(ws + 3145728);           // 3,145,728 B (absorbs tail over-read)
    float* Sh   = (float*)(ws + 6291456);           // 2 x 49152 f32 partial row sums
    float* lp   = (float*)(ws + 6684672);           // 96 f32 log partials
    float* angp = (float*)(ws + 6685056);           // 32*44 f32 angle moments

    prep_ang<<<dim3(224), dim3(256), 0, stream>>>(fourier, angles, Ap, Bp, angp);
    pair_mfma<<<dim3(1536), dim3(512), 0, stream>>>(Ap, Bp, Sh);
    log_red<<<dim3(96), dim3(512), 0, stream>>>(Sh, lp);
    final_asm<<<dim3(1), dim3(64), 0, stream>>>(angp, lp, out);
}

// Round 6
// 61.160 us; speedup vs baseline: 3.3455x; 3.3455x over previous
//
#include <hip/hip_runtime.h>
#include <math.h>

constexpr int BN = 8192;
constexpr int MN = 6;

// E = -T*log2(e)*d2 with T=2:  E = 2TL*g - TL*sq_i - TL*sq_j,  L=log2(e)
constexpr float TL    = 2.8853900817779268f;   // 2*log2(e)
constexpr float SCL_Z = 2.4022448795936154f;   // sqrt(2*T*L)

typedef __bf16 bf16_t;
typedef bf16_t bf16x8 __attribute__((ext_vector_type(8)));
typedef float f32x4 __attribute__((ext_vector_type(4)));

union PK { bf16_t h[8]; uint4 u; };

__device__ __forceinline__ bf16x8 frag_of(uint4 u) {
    return __builtin_bit_cast(bf16x8, u);
}

__device__ __host__ __forceinline__ int midx(int a, int b) {
    // index into upper-triangle (a<=b) of 8x8, row-major packed
    return 8 * a - (a * (a - 1)) / 2 + (b - a);
}

// ---------------------------------------------------------------------------
// K0: blocks 0..191  -> pack MFMA fragments (one thread per (mode, row)).
//     blocks 192..223 -> angle second moments (36 pair moments + 8 sums).
// ---------------------------------------------------------------------------
__global__ __launch_bounds__(256) void prep_ang(const float* __restrict__ x,
                                                const float* __restrict__ ang,
                                                uint4* __restrict__ Ap,
                                                uint4* __restrict__ Bp,
                                                float* __restrict__ angp) {
    const int blk = blockIdx.x;
    const int tid = threadIdx.x;
    if (blk < 192) {
        int idx = blk * 256 + tid;
        int n = idx >> 13;
        int j = idx & (BN - 1);
        const float* p = x + (size_t)j * 48 + n * 8;

        PK zh, zl, a3, b3;
        float sq = 0.f;
#pragma unroll
        for (int k = 0; k < 8; ++k) {
            float v = p[k];
            sq = fmaf(v, v, sq);
            float z = SCL_Z * v;
            bf16_t h = (bf16_t)z;
            zh.h[k] = h;
            zl.h[k] = (bf16_t)(z - (float)h);
        }
        float s = -TL * sq;
        bf16_t sh = (bf16_t)s;
        bf16_t sl = (bf16_t)(s - (float)sh);
        bf16_t one = (bf16_t)1.0f, zero = (bf16_t)0.0f;
        a3.h[0] = one; a3.h[1] = one; a3.h[2] = sh;  a3.h[3] = sl;
        b3.h[0] = sh;  b3.h[1] = sl;  b3.h[2] = one; b3.h[3] = one;
#pragma unroll
        for (int k = 4; k < 8; ++k) { a3.h[k] = zero; b3.h[k] = zero; }

        size_t base = ((size_t)(n * 512 + (j >> 4))) * 64 + (j & 15);
        Ap[base +  0] = zh.u;
        Ap[base + 16] = zl.u;
        Ap[base + 32] = zh.u;
        Ap[base + 48] = a3.u;
        Bp[base +  0] = zh.u;
        Bp[base + 16] = zh.u;
        Bp[base + 32] = zl.u;
        Bp[base + 48] = b3.u;
    } else {
        const int i = (blk - 192) * 256 + tid;  // 32 blocks cover 8192 rows
        float v[8];
#pragma unroll
        for (int k = 0; k < 4; ++k) __sincosf(ang[i * 4 + k], &v[k], &v[4 + k]);
        float acc[44];
        int c = 0;
#pragma unroll
        for (int a = 0; a < 8; ++a)
#pragma unroll
            for (int bq = a; bq < 8; ++bq) acc[c++] = v[a] * v[bq];
#pragma unroll
        for (int a = 0; a < 8; ++a) acc[36 + a] = v[a];

#pragma unroll
        for (int q = 0; q < 44; ++q) {
            float s = acc[q];
            s += __shfl_xor(s, 1);  s += __shfl_xor(s, 2);
            s += __shfl_xor(s, 4);  s += __shfl_xor(s, 8);
            s += __shfl_xor(s, 16); s += __shfl_xor(s, 32);
            acc[q] = s;
        }
        __shared__ float sm[4][44];
        const int w = tid >> 6, lane = tid & 63;
        if (lane == 0)
#pragma unroll
            for (int q = 0; q < 44; ++q) sm[w][q] = acc[q];
        __syncthreads();
        if (tid < 44)
            angp[(blk - 192) * 44 + tid] =
                sm[0][tid] + sm[1][tid] + sm[2][tid] + sm[3][tid];
    }
}

// ---------------------------------------------------------------------------
// K1: pairwise kernel.  Block = (mode, 64-row group, col-half h).
// Grid 1536 x 512thr -> 32 waves/CU theoretical (4 blocks resident).
// Wave w owns 32 CONTIGUOUS col tiles [h*256 + w*32, +32).
// Register-light inner loop: each mfma result is consumed immediately
// (R5 lesson: early-mfma arrays spilled at the 64-VGPR/8-wave budget).
// Partial row sums -> Sh[h]; diag-owning wave subtracts self-term post-loop.
// ---------------------------------------------------------------------------
__global__ __launch_bounds__(512, 8) void pair_mfma(const uint4* __restrict__ Ap,
                                                    const uint4* __restrict__ Bp,
                                                    float* __restrict__ Sh) {
    const int tid  = threadIdx.x;
    const int lane = tid & 63;
    const int w    = __builtin_amdgcn_readfirstlane(tid >> 6);
    const int b    = blockIdx.x;
    const int n    = b >> 8;          // mode
    const int rb   = (b >> 1) & 127;  // 64-row group
    const int h    = b & 1;           // column half
    const int rb4  = rb * 4;          // first 16-row tile index

    bf16x8 af[4];
#pragma unroll
    for (int t = 0; t < 4; ++t)
        af[t] = frag_of(Ap[((size_t)(n * 512 + rb4 + t)) * 64 + lane]);

    float racc[16];
#pragma unroll
    for (int q = 0; q < 16; ++q) racc[q] = 0.f;

    const uint4* bbase = Bp + ((size_t)n * 512) * 64 + lane;
    const f32x4 z4 = {0.f, 0.f, 0.f, 0.f};

    const int jt0 = h * 256 + w * 32, jt1 = jt0 + 32;
    uint4 b0 = bbase[(size_t)jt0 * 64];
    uint4 b1 = bbase[(size_t)(jt0 + 1) * 64];
    for (int jt = jt0; jt < jt1; jt += 2) {
        // prefetch depth-2; final-iter over-read (<=2 tiles) stays in ws: harmless
        uint4 p0 = bbase[(size_t)(jt + 2) * 64];
        uint4 p1 = bbase[(size_t)(jt + 3) * 64];

        bf16x8 bf = frag_of(b0);
#pragma unroll
        for (int t = 0; t < 4; ++t) {
            f32x4 d = __builtin_amdgcn_mfma_f32_16x16x32_bf16(af[t], bf, z4, 0, 0, 0);
#pragma unroll
            for (int r = 0; r < 4; ++r)
                racc[t * 4 + r] += __builtin_amdgcn_exp2f(d[r]);
        }
        bf = frag_of(b1);
#pragma unroll
        for (int t = 0; t < 4; ++t) {
            f32x4 d = __builtin_amdgcn_mfma_f32_16x16x32_bf16(af[t], bf, z4, 0, 0, 0);
#pragma unroll
            for (int r = 0; r < 4; ++r)
                racc[t * 4 + r] += __builtin_amdgcn_exp2f(d[r]);
        }
        b0 = p0; b1 = p1;
    }

    // diagonal fix-up: all 4 diag tiles (rb4..rb4+3, rb4 % 4 == 0) sit inside
    // one 32-tile window -> exactly one wave runs this (wave-uniform).
    if ((rb4 >> 8) == h && ((rb4 >> 5) & 7) == w) {
        const int dd = (lane & 15) - 4 * (lane >> 4);
#pragma unroll
        for (int t = 0; t < 4; ++t) {
            bf16x8 bf = frag_of(bbase[(size_t)(rb4 + t) * 64]);
            f32x4 d = __builtin_amdgcn_mfma_f32_16x16x32_bf16(af[t], bf, z4, 0, 0, 0);
#pragma unroll
            for (int r = 0; r < 4; ++r)
                if (dd == r) racc[t * 4 + r] -= __builtin_amdgcn_exp2f(d[r]);
        }
    }

    // reduce each racc over the 16 lanes of its column group (low 4 lane bits)
#pragma unroll
    for (int q = 0; q < 16; ++q) {
        float v = racc[q];
        v += __shfl_xor(v, 1);
        v += __shfl_xor(v, 2);
        v += __shfl_xor(v, 4);
        v += __shfl_xor(v, 8);
        racc[q] = v;
    }

    __shared__ float smem[8][64];
    if ((lane & 15) == 0) {
        int g = lane >> 4;
#pragma unroll
        for (int t = 0; t < 4; ++t)
#pragma unroll
            for (int r = 0; r < 4; ++r)
                smem[w][t * 16 + g * 4 + r] = racc[t * 4 + r];
    }
    __syncthreads();

    if (tid < 64) {
        float s = 0.f;
#pragma unroll
        for (int ww = 0; ww < 8; ++ww) s += smem[ww][tid];
        Sh[h * (MN * BN) + n * BN + rb * 64 + tid] = s;
    }
}

// ---------------------------------------------------------------------------
// K2: merge halves, take log, per-block partial sums.  96 blocks x 512.
// ---------------------------------------------------------------------------
__global__ __launch_bounds__(512) void log_red(const float* __restrict__ Sh,
                                               float* __restrict__ lp) {
    const int tid = threadIdx.x;
    const int idx = blockIdx.x * 512 + tid;
    float v = Sh[idx] + Sh[idx + MN * BN];
    float lg = logf(v);
    lg += __shfl_xor(lg, 1);
    lg += __shfl_xor(lg, 2);
    lg += __shfl_xor(lg, 4);
    lg += __shfl_xor(lg, 8);
    lg += __shfl_xor(lg, 16);
    lg += __shfl_xor(lg, 32);
    __shared__ float sm[8];
    if ((tid & 63) == 0) sm[tid >> 6] = lg;
    __syncthreads();
    if (tid == 0) {
        float s = 0.f;
#pragma unroll
        for (int i = 0; i < 8; ++i) s += sm[i];
        lp[blockIdx.x] = s;
    }
}

// ---------------------------------------------------------------------------
// K3: final assembly — mu/cov/spread from moments, per-mode unif, outputs.
// ---------------------------------------------------------------------------
__global__ __launch_bounds__(64) void final_asm(const float* __restrict__ angp,
                                                const float* __restrict__ lp,
                                                float* __restrict__ out) {
    const int tid = threadIdx.x;
    __shared__ float mom[44];

    if (tid < 44) {
        float s = 0.f;
        for (int bk = 0; bk < 32; ++bk) s += angp[bk * 44 + tid];
        mom[tid] = s;
    }
    __syncthreads();

    if (tid == 0) {
        float sm[4], cm[4];
#pragma unroll
        for (int k = 0; k < 4; ++k) {
            float S = mom[36 + k], C = mom[40 + k];
            float hyp = sqrtf(S * S + C * C);
            sm[k] = S / hyp;       // sin(mu_k)
            cm[k] = C / hyp;       // cos(mu_k)
        }
        auto COV = [&](int k, int l) -> float {
            int ks = k < l ? k : l, kl = k < l ? l : k;
            float mss = mom[midx(ks, kl)];
            float msc_kl = mom[midx(k, l + 4)];
            float msc_lk = mom[midx(l, k + 4)];
            float mcc = mom[midx(ks + 4, kl + 4)];
            return (cm[k] * cm[l] * mss - cm[k] * sm[l] * msc_kl -
                    sm[k] * cm[l] * msc_lk + sm[k] * sm[l] * mcc) *
                   (1.0f / (float)BN);
        };
        float var[4] = {COV(0, 0), COV(1, 1), COV(2, 2), COV(3, 3)};
        float spread = 0.f;
        const int pk[6] = {0, 0, 0, 1, 1, 2};
        const int pl[6] = {1, 2, 3, 2, 3, 3};
#pragma unroll
        for (int p = 0; p < 6; ++p) {
            float cv = COV(pk[p], pl[p]);
            float den = sqrtf(var[pk[p]] * var[pl[p]] + 1e-8f);
            float cr = cv / den;
            spread += cr * cr;
        }
        spread *= (1.0f / 6.0f);

        const float wgt[6] = {0.0f, 0.19615242270663188f, 0.4641016151377544f,
                              0.7320508075688773f, 0.9282032302755088f, 1.0f};
        const float logBm1 = logf((float)(BN - 1));
        float total_unif = 0.f, unif[6];
#pragma unroll
        for (int m = 0; m < 6; ++m) {
            float s = 0.f;
            for (int i = 0; i < 16; ++i) s += lp[m * 16 + i];
            unif[m] = s * (1.0f / (float)BN) - logBm1;
            total_unif += wgt[m] * unif[m];
        }
        out[0] = total_unif;
        out[1] = spread;
        out[2] = total_unif + spread;
#pragma unroll
        for (int m = 0; m < 6; ++m) out[3 + m] = unif[m];
    }
}

extern "C" void kernel_launch(void* const* d_in, const int* in_sizes, int n_in,
                              void* d_out, int out_size, void* d_ws, size_t ws_size,
                              hipStream_t stream) {
    const float* angles  = (const float*)d_in[0];   // (8192, 4) f32
    const float* fourier = (const float*)d_in[1];   // (8192, 48) f32
    float* out = (float*)d_out;                     // 9 floats

    char* ws = (char*)d_ws;
    uint4* Bp   = (uint4*)(ws + 0);                 // 3,145,728 B
    uint4* Ap   = (uint4*)(ws + 3145728);           // 3,145,728 B (absorbs tail over-read)
    float* Sh   = (float*)(ws + 6291456);           // 2 x 49152 f32 partial row sums
    float* lp   = (float*)(ws + 6684672);           // 96 f32 log partials
    float* angp = (float*)(ws + 6685056);           // 32*44 f32 angle moments

    prep_ang<<<dim3(224), dim3(256), 0, stream>>>(fourier, angles, Ap, Bp, angp);
    pair_mfma<<<dim3(1536), dim3(512), 0, stream>>>(Ap, Bp, Sh);
    log_red<<<dim3(96), dim3(512), 0, stream>>>(Sh, lp);
    final_asm<<<dim3(1), dim3(64), 0, stream>>>(angp, lp, out);
}